// Round 15
// baseline (414.548 us; speedup 1.0000x reference)
//
#include <hip/hip_runtime.h>
#include <math.h>

#define Nn 16384
#define Dd 128
#define Kk 32
#define JSPLIT 8
#define JCH (Nn / JSPLIT)     // 2048 j per chunk
#define NG (JCH / 16)         // 128 groups of 16 j per chunk
#define CAP 32                // cand slots per (row, chunk); true mean ~10.3 (6.8 sigma)
#define MAXSLOT 2             // exact-pass capacity 128 (true mean M~82, 5.1 sigma)
#define BAND 0.4f             // 2x bound on hi-bf16 approx rv error (validated r4-r11)
#define PMARG 1.0f            // preselect window: 2x (BAND + f16-storage err 0.04) rounded up
#define ZQ 2.4176f            // validated: true E[count]~82 (chi-square left tail);
                              // r16's 2.60 gave E~44 -> cleanup blowup. Do not raise.

typedef unsigned short u16;
typedef unsigned u32;
typedef short short8 __attribute__((ext_vector_type(8)));
typedef float f32x4 __attribute__((ext_vector_type(4)));

__device__ __forceinline__ u16 f2bf(float x) {
    unsigned u = __float_as_uint(x);
    unsigned r = u + 0x7FFFu + ((u >> 16) & 1u);   // RN-even
    return (u16)(r >> 16);
}

// --------------- prep: bf16 convert + sqn + analytic threshold + flag=0 ----
__global__ __launch_bounds__(256) void prep_kernel(const float* __restrict__ X,
                                                   u16* __restrict__ Xhi,
                                                   float* __restrict__ sqn,
                                                   float* __restrict__ thrA,
                                                   int* __restrict__ flagCnt) {
    const int i = blockIdx.x * 4 + (threadIdx.x >> 6);
    const int lane = threadIdx.x & 63;
    const float2 v = *(const float2*)(X + (size_t)i * Dd + lane * 2);
    const unsigned pack = ((unsigned)f2bf(v.y) << 16) | (unsigned)f2bf(v.x);
    *(unsigned*)(Xhi + (size_t)i * Dd + lane * 2) = pack;
    float s = fmaf(v.x, v.x, v.y * v.y);
#pragma unroll
    for (int o = 32; o > 0; o >>= 1) s += __shfl_down(s, o);
    if (lane == 0) {
        sqn[i] = s;
        // rv = sqn_j - 2 xi.xj ~ N(128, 256 + 4*sqn_i); keep rv < thr
        thrA[i] = 128.0f - ZQ * sqrtf(256.0f + 4.0f * s);
    }
    if (blockIdx.x == 0 && threadIdx.x == 0) *flagCnt = 0;
}

// ----------------------------------------------------------- knn filter ----
// r23: REVERT to the r20 form (HW-validated 152.2us, total 366.6). r22's
// JSPLIT=16 kept occupancy at 2 waves/SIMD (effective regs incl. AGPR >128)
// and added block overhead. Probe series complete (7 levers, all null/neg):
// this structure's ~152us is the floor. Packed (j | apx<<16) u32 slots, one
// ds_write_b32 per slot, bias-fold C-init, branchless predicated tail.
__global__ __launch_bounds__(256, 2) void knn_filter(const u16* __restrict__ Xhi,
                                                     const float* __restrict__ sqn,
                                                     const float* __restrict__ thrA,
                                                     u32* __restrict__ candA,
                                                     int* __restrict__ candCnt) {
    __shared__ u32 listP[256 * CAP + 256];   // packed slots + scrap (33.8 KB)
    __shared__ int cntS[256];

    const int tid = threadIdx.x;
    const int wave = tid >> 6, lane = tid & 63;
    const int quad = lane >> 4, n16 = lane & 15;
    const int itile = blockIdx.x >> 3, chunk = blockIdx.x & 7;
    const int ibase = itile * 256;
    const int wbase = ibase + wave * 64;
    const int jch0 = chunk * JCH;
    const unsigned below = (1u << n16) - 1u;
    const int scrapOff = 256 * CAP + tid;    // per-thread scrap slot

    short8 aF[4][4];
#pragma unroll
    for (int is = 0; is < 4; is++) {
        const u16* arow = Xhi + (size_t)(wbase + is * 16 + n16) * Dd + quad * 8;
#pragma unroll
        for (int ks = 0; ks < 4; ks++) aF[is][ks] = *(const short8*)(arow + ks * 32);
    }
    float nhT[16];                    // -thr/2 per owned row
    int cntReg[16];
#pragma unroll
    for (int is = 0; is < 4; is++)
#pragma unroll
        for (int r = 0; r < 4; r++) {
            nhT[is * 4 + r] = -0.5f * thrA[wbase + is * 16 + quad * 4 + r];
            cntReg[is * 4 + r] = 0;
        }

    const u16* bbase = Xhi + (size_t)(jch0 + n16) * Dd + quad * 8;
    short8 bb[2][4];
    float sj[2];
#pragma unroll
    for (int ks = 0; ks < 4; ks++) bb[0][ks] = *(const short8*)(bbase + ks * 32);
    sj[0] = sqn[jch0 + n16];
#pragma unroll
    for (int ks = 0; ks < 4; ks++) bb[1][ks] = *(const short8*)(bbase + 16 * Dd + ks * 32);
    sj[1] = sqn[jch0 + 16 + n16];

    // acc = dot(i,j) - 0.5*sj  (bias in C-init); rv = -2*acc
    // hit: rv < thr  <=>  acc > -thr/2 = nhT
#define MSTEP(p, gg)                                                           \
    {                                                                          \
        const float bias = -0.5f * sj[p];                                      \
        acc##p[0] = (f32x4){bias, bias, bias, bias};                           \
        acc##p[1] = acc##p[0]; acc##p[2] = acc##p[0]; acc##p[3] = acc##p[0];   \
        _Pragma("unroll")                                                      \
        for (int ks = 0; ks < 4; ks++) {                                       \
            acc##p[0] = __builtin_amdgcn_mfma_f32_16x16x32_bf16(aF[0][ks], bb[p][ks], acc##p[0], 0, 0, 0); \
            acc##p[1] = __builtin_amdgcn_mfma_f32_16x16x32_bf16(aF[1][ks], bb[p][ks], acc##p[1], 0, 0, 0); \
            acc##p[2] = __builtin_amdgcn_mfma_f32_16x16x32_bf16(aF[2][ks], bb[p][ks], acc##p[2], 0, 0, 0); \
            acc##p[3] = __builtin_amdgcn_mfma_f32_16x16x32_bf16(aF[3][ks], bb[p][ks], acc##p[3], 0, 0, 0); \
        }                                                                      \
        {   /* unconditional distance-2 prefetch: Xhi/sqn padded past end */   \
            const u16* nb = bbase + (size_t)((gg) + 2) * 16 * Dd;              \
            bb[p][0] = *(const short8*)(nb);                                   \
            bb[p][1] = *(const short8*)(nb + 32);                              \
            bb[p][2] = *(const short8*)(nb + 64);                              \
            bb[p][3] = *(const short8*)(nb + 96);                              \
            sj[p] = sqn[jch0 + ((gg) + 2) * 16 + n16];                         \
        }                                                                      \
    }

#define TSTEP(p, gg)                                                           \
    {                                                                          \
        const int jj = jch0 + (gg) * 16 + n16;                                 \
        _Pragma("unroll")                                                      \
        for (int is = 0; is < 4; is++) {                                       \
            _Pragma("unroll")                                                  \
            for (int r = 0; r < 4; r++) {                                      \
                const int ir = is * 4 + r;                                     \
                const float av = acc##p[is][r];                                \
                const bool h = av > nhT[ir];                                   \
                const unsigned long long mr = __ballot(h);                     \
                const unsigned qm = (unsigned)(mr >> (quad * 16)) & 0xFFFFu;   \
                const int pos = cntReg[ir] + __popc(qm & below);               \
                const bool wr = h && (pos < CAP);                              \
                const int rowbase = (wave * 64 + is * 16 + quad * 4 + r) * CAP; \
                const int off = wr ? rowbase + pos : scrapOff;                 \
                const u32 pk = (u32)(u16)jj |                                  \
                    ((u32)__builtin_bit_cast(unsigned short, (_Float16)av) << 16); \
                listP[off] = pk;            /* unconditional, predicated addr */ \
                cntReg[ir] += __popc(qm);                                      \
            }                                                                  \
        }                                                                      \
    }

    f32x4 acc0[4], acc1[4];
    MSTEP(0, 0)
    for (int g = 0; g < NG - 2; g += 2) {
        MSTEP(1, g + 1)
        TSTEP(0, g)
        MSTEP(0, g + 2)
        TSTEP(1, g + 1)
    }
    MSTEP(1, NG - 1)
    TSTEP(0, NG - 2)
    TSTEP(1, NG - 1)
#undef MSTEP
#undef TSTEP

    if (n16 == 0) {
#pragma unroll
        for (int is = 0; is < 4; is++)
#pragma unroll
            for (int r = 0; r < 4; r++)
                cntS[wave * 64 + is * 16 + quad * 4 + r] = cntReg[is * 4 + r];
    }
    for (int rl = 0; rl < 64; rl++) {
        const int row = wave * 64 + rl;
        const int n = cntS[row];            // same-wave LDS: no barrier needed
        const int gi = ibase + row;
        if (lane == 0) candCnt[(size_t)gi * JSPLIT + chunk] = n;  // raw (overflow signal)
        if (lane < min(n, CAP))
            candA[((size_t)gi * JSPLIT + chunk) * CAP + lane] = listP[row * CAP + lane];
    }
}

// ----------------------------------------------------------- knn exact -----
// r20 (kept): approx-preselect with packed-u32 gather (j = lo16, apx f16 =
// hi16). S = {apx_rv <= t32 + PMARG} provably contains every true top-32
// member; Phase B exact path identical to r18 -> idx bit-identical.
__global__ __launch_bounds__(256) void knn_exact(const float* __restrict__ X,
                                                 const float* __restrict__ sqn,
                                                 const float* __restrict__ thrA,
                                                 const u32* __restrict__ candA,
                                                 const int* __restrict__ candCnt,
                                                 int* __restrict__ idx_out,
                                                 int* __restrict__ flagCnt,
                                                 int* __restrict__ flagRows) {
    __shared__ u16 sjd[4][128];              // compacted S j-lists, per wave
    const int wave = threadIdx.x >> 6, lane = threadIdx.x & 63;
    const int quad = lane >> 4, n16 = lane & 15;
    const int i = blockIdx.x * 4 + wave;

    // xi quarter (32 floats) in registers; broadcast within quad
    float4 xi[8];
    {
        const float4* xb = (const float4*)(X + (size_t)i * Dd + quad * 32);
#pragma unroll
        for (int u = 0; u < 8; u++) xi[u] = xb[u];
    }
    int pre[JSPLIT];
    bool over = false;
    int M = 0;
#pragma unroll
    for (int k = 0; k < JSPLIT; k++) {
        int c = candCnt[(size_t)i * JSPLIT + k];
        over = over || (c > CAP);
        pre[k] = M;
        M += min(c, CAP);
    }
    over = over || (M > 64 * MAXSLOT);
    if (over) {
        if (lane == 0) { const int f = atomicAdd(flagCnt, 1); flagRows[f] = i; }
        return;
    }
    const float rvT = thrA[i];

    // ---- Phase A: one packed gather; rank approx rv in-register
    float ra[MAXSLOT];
    int jdA[MAXSLOT];
#pragma unroll
    for (int s = 0; s < MAXSLOT; s++) {
        const int c = s * 64 + lane;
        if (c < M) {
            int k = 0;
#pragma unroll
            for (int q = 1; q < JSPLIT; q++) if (c >= pre[q]) k = q;
            const u32 v = candA[((size_t)i * JSPLIT + k) * CAP + (c - pre[k])];
            jdA[s] = (int)(v & 0xFFFFu);
            const _Float16 hf = __builtin_bit_cast(_Float16, (unsigned short)(v >> 16));
            ra[s] = -2.0f * (float)hf;       // approx rv
        } else { ra[s] = INFINITY; jdA[s] = -1; }
    }
    int rkA[MAXSLOT] = {};
    for (int s2 = 0; s2 < 64; s2++) {
        const float o0 = __shfl(ra[0], s2), o1 = __shfl(ra[1], s2);
#pragma unroll
        for (int s = 0; s < MAXSLOT; s++) {
            const int myid = lane + 64 * s;
            rkA[s] += (o0 < ra[s] || (o0 == ra[s] && s2 < myid)) ? 1 : 0;
            rkA[s] += (o1 < ra[s] || (o1 == ra[s] && s2 + 64 < myid)) ? 1 : 0;
        }
    }
    float t32 = INFINITY;
    if (M >= Kk) {
        const unsigned long long m0 = __ballot(rkA[0] == Kk - 1);
        if (m0) t32 = __shfl(ra[0], __ffsll(m0) - 1);
        else {
            const unsigned long long m1 = __ballot(rkA[1] == Kk - 1);
            t32 = __shfl(ra[1], __ffsll(m1) - 1);
        }
    }
    const float wEnd = t32 + PMARG;

    // ---- compact S into LDS (slot order preserved -> tiebreak order kept)
    int ns;
    {
        const bool sel0 = ra[0] <= wEnd;
        const unsigned long long b0 = __ballot(sel0);
        const int c0 = __popcll(b0);
        const int p0 = __popcll(b0 & ((1ull << lane) - 1ull));
        const bool sel1 = ra[1] <= wEnd;
        const unsigned long long b1 = __ballot(sel1);
        const int p1 = c0 + __popcll(b1 & ((1ull << lane) - 1ull));
        ns = c0 + __popcll(b1);
        if (sel0) sjd[wave][p0] = (u16)jdA[0];
        if (sel1) sjd[wave][p1] = (u16)jdA[1];
    }

    // ---- Phase B: exact gather over S only (same numerics as r18)
    float rv[MAXSLOT];
    int jd[MAXSLOT];
#pragma unroll
    for (int s = 0; s < MAXSLOT; s++) { rv[s] = INFINITY; jd[s] = -1; }

#pragma unroll
    for (int s = 0; s < MAXSLOT; s++) {
#pragma unroll
        for (int t = 0; t < 4; t++) {
            const int c = s * 64 + t * 16 + n16;
            if (c < ns) {
                const int jj = sjd[wave][c];
                const float4* xb = (const float4*)(X + (size_t)jj * Dd + quad * 32);
                float s0 = 0.f, s1 = 0.f, s2 = 0.f, s3 = 0.f;
#pragma unroll
                for (int u = 0; u < 8; u++) {
                    const float4 b = xb[u];
                    s0 = fmaf(xi[u].x, b.x, s0); s1 = fmaf(xi[u].y, b.y, s1);
                    s2 = fmaf(xi[u].z, b.z, s2); s3 = fmaf(xi[u].w, b.w, s3);
                }
                float p = (s0 + s1) + (s2 + s3);
                p += __shfl_xor(p, 16);
                p += __shfl_xor(p, 32);
                if (quad == t) { rv[s] = fmaf(-2.f, p, sqn[jj]); jd[s] = jj; }
            }
        }
    }

    int good = 0;
#pragma unroll
    for (int s = 0; s < MAXSLOT; s++) good += __popcll(__ballot(rv[s] < rvT - BAND));
    if (good < Kk) {   // insufficient evidence -> exact cleanup path
        if (lane == 0) { const int f = atomicAdd(flagCnt, 1); flagRows[f] = i; }
        return;
    }
    int rk[MAXSLOT] = {};
    for (int s2 = 0; s2 < 64; s2++) {
        float ov[MAXSLOT];
#pragma unroll
        for (int s = 0; s < MAXSLOT; s++) ov[s] = __shfl(rv[s], s2);
#pragma unroll
        for (int s = 0; s < MAXSLOT; s++) {
            const int myid = lane + 64 * s;
#pragma unroll
            for (int t = 0; t < MAXSLOT; t++)
                rk[s] += (ov[t] < rv[s] || (ov[t] == rv[s] && s2 + 64 * t < myid)) ? 1 : 0;
        }
    }
#pragma unroll
    for (int s = 0; s < MAXSLOT; s++)
        if (jd[s] >= 0 && rk[s] < Kk) idx_out[(size_t)i * Kk + rk[s]] = jd[s];
}

// ----------------------------------------------------------- knn cleanup ---
// Exact fp32 full-scan top-32 for flagged rows (expected: none).
__global__ __launch_bounds__(256) void knn_cleanup(const float* __restrict__ X,
                                                   const float* __restrict__ sqn,
                                                   const int* __restrict__ flagCnt,
                                                   const int* __restrict__ flagRows,
                                                   float* __restrict__ scratch,
                                                   int* __restrict__ idx_out) {
    __shared__ float xi[Dd];
    __shared__ int cntS;
    __shared__ float lv[256];
    __shared__ int lj[256];
    const int tid = threadIdx.x;
    const int lane = tid & 63;
    const int F = *flagCnt;
    float* rvS = scratch + (size_t)blockIdx.x * Nn;
    for (int f = blockIdx.x; f < F; f += gridDim.x) {
        const int i = flagRows[f];
        __syncthreads();
        if (tid < Dd) xi[tid] = X[(size_t)i * Dd + tid];
        __syncthreads();
        for (int j = tid; j < Nn; j += 256) {
            const float* xj = X + (size_t)j * Dd;
            float s0 = 0.f, s1 = 0.f, s2 = 0.f, s3 = 0.f;
#pragma unroll
            for (int d = 0; d < Dd; d += 4) {
                const float4 a = *(const float4*)&xi[d];
                const float4 b = *(const float4*)(xj + d);
                s0 = fmaf(a.x, b.x, s0); s1 = fmaf(a.y, b.y, s1);
                s2 = fmaf(a.z, b.z, s2); s3 = fmaf(a.w, b.w, s3);
            }
            rvS[j] = fmaf(-2.f, (s0 + s1) + (s2 + s3), sqn[j]);
        }
        __syncthreads();
        float lo = -1.0e9f, hi = 1.0e9f, T = 1.0e9f;
        for (int it = 0; it < 48; it++) {
            const float mid = 0.5f * (lo + hi);
            int local = 0;
            for (int j = tid; j < Nn; j += 256) local += (rvS[j] < mid) ? 1 : 0;
#pragma unroll
            for (int o = 32; o > 0; o >>= 1) local += __shfl_down(local, o);
            __syncthreads();
            if (tid == 0) cntS = 0;
            __syncthreads();
            if (lane == 0) atomicAdd(&cntS, local);
            __syncthreads();
            const int c = cntS;
            if (c < Kk) lo = mid;
            else if (c > 200) hi = mid;
            else { T = mid; break; }
        }
        if (T == 1.0e9f) T = hi;
        __syncthreads();
        if (tid == 0) cntS = 0;
        __syncthreads();
        for (int j = tid; j < Nn; j += 256) {
            if (rvS[j] < T) {
                const int p = atomicAdd(&cntS, 1);
                if (p < 256) { lv[p] = rvS[j]; lj[p] = j; }
            }
        }
        __syncthreads();
        const int n = min(cntS, 256);
        if (tid < 64) {
            float v[4]; int jjj[4]; int rk2[4] = {0, 0, 0, 0};
#pragma unroll
            for (int s = 0; s < 4; s++) {
                const int sl = lane + 64 * s;
                v[s] = (sl < n) ? lv[sl] : INFINITY;
                jjj[s] = (sl < n) ? lj[sl] : -1;
            }
            for (int s2 = 0; s2 < 64; s2++) {
                const float o0 = __shfl(v[0], s2), o1 = __shfl(v[1], s2);
                const float o2 = __shfl(v[2], s2), o3 = __shfl(v[3], s2);
#pragma unroll
                for (int s = 0; s < 4; s++) {
                    const int myid = lane + 64 * s;
                    rk2[s] += (o0 < v[s] || (o0 == v[s] && s2 < myid));
                    rk2[s] += (o1 < v[s] || (o1 == v[s] && s2 + 64 < myid));
                    rk2[s] += (o2 < v[s] || (o2 == v[s] && s2 + 128 < myid));
                    rk2[s] += (o3 < v[s] || (o3 == v[s] && s2 + 192 < myid));
                }
            }
#pragma unroll
            for (int s = 0; s < 4; s++)
                if (jjj[s] >= 0 && rk2[s] < Kk) idx_out[(size_t)i * Kk + rk2[s]] = jjj[s];
        }
        __syncthreads();
    }
}

// ------------------------------------------------- P = X@(W1a-W1b)+b1, Q = X@W1b
// r23: 64 rows/block (grid 256): W1 re-read 67 -> 34 MB. Same fmaf order per
// row -> P/Q bit-identical.
__global__ __launch_bounds__(256) void pq_kernel(const float* __restrict__ X,
                                                 const float* __restrict__ W1,
                                                 const float* __restrict__ b1,
                                                 float* __restrict__ P,
                                                 float* __restrict__ Q) {
    __shared__ float xrow[64][Dd];   // 32 KB
    const int i0 = blockIdx.x * 64;
    for (int t = threadIdx.x; t < 64 * Dd / 4; t += 256)
        ((float4*)&xrow[0][0])[t] = ((const float4*)(X + (size_t)i0 * Dd))[t];
    __syncthreads();
    const int cc = threadIdx.x & 127;
    const int mat = threadIdx.x >> 7;
    float acc[64];
#pragma unroll
    for (int r = 0; r < 64; r++) acc[r] = 0.f;
    for (int d = 0; d < Dd; d++) {
        float w;
        if (mat == 0) w = W1[d * 128 + cc] - W1[(128 + d) * 128 + cc];
        else          w = W1[(128 + d) * 128 + cc];
#pragma unroll
        for (int r = 0; r < 64; r++) acc[r] = fmaf(xrow[r][d], w, acc[r]);
    }
    if (mat == 0) {
        const float b = b1[cc];
#pragma unroll
        for (int r = 0; r < 64; r++) P[(size_t)(i0 + r) * 128 + cc] = acc[r] + b;
    } else {
#pragma unroll
        for (int r = 0; r < 64; r++) Q[(size_t)(i0 + r) * 128 + cc] = acc[r];
    }
}

// ------- r19 FUSED (kept): h1 in-LDS, then P2/Q2. Deletes h1 kernel + 16 MB.
__global__ __launch_bounds__(256) void pq2_kernel(const float* __restrict__ P,
                                                  const float* __restrict__ Q,
                                                  const int* __restrict__ idx,
                                                  const float* __restrict__ W2,
                                                  const float* __restrict__ b2,
                                                  float* __restrict__ P2,
                                                  float* __restrict__ Q2) {
    __shared__ float w2s[2560];        // 256 x 10, linear
    __shared__ float h1s[16][132];
    __shared__ int jbS[16][Kk];        // 2 KB
    const int i0 = blockIdx.x * 16;
    const int tid = threadIdx.x;
    for (int t = tid; t < 640; t += 256)
        ((float4*)w2s)[t] = ((const float4*)W2)[t];
    ((int2*)&jbS[0][0])[tid] = ((const int2*)(idx + (size_t)i0 * Kk))[tid];  // 512 ints
    __syncthreads();
    {   // h1 rows in LDS: thread -> (row r, 8 cols at c0)
        const int r = tid >> 4, c0 = (tid & 15) * 8;
        float4 m0 = {-INFINITY, -INFINITY, -INFINITY, -INFINITY}, m1 = m0;
        for (int k = 0; k < Kk; k++) {
            const int jb = jbS[r][k];
            const float4* qb = (const float4*)(Q + (size_t)jb * 128 + c0);
            const float4 a = qb[0], b = qb[1];
            m0.x = fmaxf(m0.x, a.x); m0.y = fmaxf(m0.y, a.y);
            m0.z = fmaxf(m0.z, a.z); m0.w = fmaxf(m0.w, a.w);
            m1.x = fmaxf(m1.x, b.x); m1.y = fmaxf(m1.y, b.y);
            m1.z = fmaxf(m1.z, b.z); m1.w = fmaxf(m1.w, b.w);
        }
        const float4* pb = (const float4*)(P + (size_t)(i0 + r) * 128 + c0);
        const float4 pa = pb[0], pc = pb[1];
        h1s[r][c0 + 0] = fmaxf(pa.x + m0.x, 0.f);
        h1s[r][c0 + 1] = fmaxf(pa.y + m0.y, 0.f);
        h1s[r][c0 + 2] = fmaxf(pa.z + m0.z, 0.f);
        h1s[r][c0 + 3] = fmaxf(pa.w + m0.w, 0.f);
        h1s[r][c0 + 4] = fmaxf(pc.x + m1.x, 0.f);
        h1s[r][c0 + 5] = fmaxf(pc.y + m1.y, 0.f);
        h1s[r][c0 + 6] = fmaxf(pc.z + m1.z, 0.f);
        h1s[r][c0 + 7] = fmaxf(pc.w + m1.w, 0.f);
    }
    __syncthreads();
    const int il = tid >> 4, c = tid & 15;
    if (c >= 10) return;
    float pa = 0.f, pb = 0.f;
#pragma unroll 4
    for (int d = 0; d < Dd; d++) {
        const float h = h1s[il][d];
        const float wa = w2s[d * 10 + c];
        const float wb = w2s[(128 + d) * 10 + c];
        pa = fmaf(h, wa - wb, pa);
        pb = fmaf(h, wb, pb);
    }
    P2[(size_t)(i0 + il) * 10 + c] = pa + b2[c];
    Q2[(size_t)(i0 + il) * 10 + c] = pb;
}

// ---------------------------------- out = P2 + max_k Q2[idx] (no relu) ------
__global__ __launch_bounds__(256) void out_kernel(const float* __restrict__ P2,
                                                  const float* __restrict__ Q2,
                                                  const int* __restrict__ idx,
                                                  float* __restrict__ out) {
    const int g = blockIdx.x * 256 + threadIdx.x;
    const int i = g >> 4;
    const int c = g & 15;
    if (c >= 10) return;
    const int* jr = idx + (size_t)i * Kk;
    float m = -INFINITY;
#pragma unroll
    for (int k = 0; k < Kk; k++) m = fmaxf(m, Q2[(size_t)jr[k] * 10 + c]);
    out[(size_t)i * 10 + c] = P2[(size_t)i * 10 + c] + m;
}

extern "C" void kernel_launch(void* const* d_in, const int* in_sizes, int n_in,
                              void* d_out, int out_size, void* d_ws, size_t ws_size,
                              hipStream_t stream) {
    const float* X  = (const float*)d_in[0];
    const float* W1 = (const float*)d_in[1];
    const float* b1 = (const float*)d_in[2];
    const float* W2 = (const float*)d_in[3];
    const float* b2 = (const float*)d_in[4];
    float* out = (float*)d_out;

    char* ws = (char*)d_ws;
    float* sqn     = (float*)(ws + 0);            // 64 KB + pad (prefetch overrun)
    float* thrA    = (float*)(ws + 73728);        // 64 KB
    int*   flagCnt = (int*)(ws + 139264);         // 128 B
    int*   flagRows= (int*)(ws + 139392);         // 64 KB
    int*   idx     = (int*)(ws + 262144);         // 2 MB
    u16*   Xhi     = (u16*)(ws + 2359296);        // (16384+32)*256 B (padded)
    float* P       = (float*)(ws + 6561792);      // 8 MB
    float* Q       = P + (size_t)Nn * 128;        // 8 MB
    // h1 array DELETED (fused into pq2); its 8 MB hole holds candCnt.
    float* P2      = P + (size_t)3 * Nn * 128;    // 640 KB (old offset kept)
    float* Q2      = P2 + (size_t)Nn * 10;        // 640 KB
    // candA packed u32 (16.78 MB) aliases the P+Q span EXACTLY
    // (Nn*8*32*4 B == 2*Nn*128*4 B); dead before pq writes P/Q. candCnt
    // (512 KB) in the h1 hole. cleanup scratch aliases P+Q (candA dead then).
    u32* candA   = (u32*)P;
    int* candCnt = (int*)((char*)P + (size_t)2 * Nn * 128 * 4);  // h1 hole
    float* cleanupScratch = P;                    // 256 blocks x 64 KB = 16 MB

    prep_kernel<<<Nn / 4, 256, 0, stream>>>(X, Xhi, sqn, thrA, flagCnt);
    knn_filter<<<64 * JSPLIT, 256, 0, stream>>>(Xhi, sqn, thrA, candA, candCnt);
    knn_exact<<<Nn / 4, 256, 0, stream>>>(X, sqn, thrA, candA, candCnt, idx, flagCnt, flagRows);
    knn_cleanup<<<256, 256, 0, stream>>>(X, sqn, flagCnt, flagRows, cleanupScratch, idx);
    pq_kernel<<<Nn / 64, 256, 0, stream>>>(X, W1, b1, P, Q);
    pq2_kernel<<<Nn / 16, 256, 0, stream>>>(P, Q, idx, W2, b2, P2, Q2);
    out_kernel<<<Nn * 16 / 256, 256, 0, stream>>>(P2, Q2, idx, out);
}

// Round 16
// 367.984 us; speedup vs baseline: 1.1265x; 1.1265x over previous
//
#include <hip/hip_runtime.h>
#include <math.h>

#define Nn 16384
#define Dd 128
#define Kk 32
#define JSPLIT 8
#define JCH (Nn / JSPLIT)     // 2048 j per chunk
#define NG (JCH / 16)         // 128 groups of 16 j per chunk
#define CAP 32                // cand slots per (row, chunk); true mean ~10.3 (6.8 sigma)
#define MAXSLOT 2             // exact-pass capacity 128 (true mean M~82, 5.1 sigma)
#define BAND 0.4f             // 2x bound on hi-bf16 approx rv error (validated r4-r11)
#define PMARG 1.0f            // preselect window: 2x (BAND + f16-storage err 0.04) rounded up
#define ZQ 2.4176f            // validated: true E[count]~82 (chi-square left tail);
                              // r16's 2.60 gave E~44 -> cleanup blowup. Do not raise.

typedef unsigned short u16;
typedef unsigned u32;
typedef short short8 __attribute__((ext_vector_type(8)));
typedef float f32x4 __attribute__((ext_vector_type(4)));

__device__ __forceinline__ u16 f2bf(float x) {
    unsigned u = __float_as_uint(x);
    unsigned r = u + 0x7FFFu + ((u >> 16) & 1u);   // RN-even
    return (u16)(r >> 16);
}

// --------------- prep: bf16 convert + sqn + analytic threshold + flag=0 ----
__global__ __launch_bounds__(256) void prep_kernel(const float* __restrict__ X,
                                                   u16* __restrict__ Xhi,
                                                   float* __restrict__ sqn,
                                                   float* __restrict__ thrA,
                                                   int* __restrict__ flagCnt) {
    const int i = blockIdx.x * 4 + (threadIdx.x >> 6);
    const int lane = threadIdx.x & 63;
    const float2 v = *(const float2*)(X + (size_t)i * Dd + lane * 2);
    const unsigned pack = ((unsigned)f2bf(v.y) << 16) | (unsigned)f2bf(v.x);
    *(unsigned*)(Xhi + (size_t)i * Dd + lane * 2) = pack;
    float s = fmaf(v.x, v.x, v.y * v.y);
#pragma unroll
    for (int o = 32; o > 0; o >>= 1) s += __shfl_down(s, o);
    if (lane == 0) {
        sqn[i] = s;
        // rv = sqn_j - 2 xi.xj ~ N(128, 256 + 4*sqn_i); keep rv < thr
        thrA[i] = 128.0f - ZQ * sqrtf(256.0f + 4.0f * s);
    }
    if (blockIdx.x == 0 && threadIdx.x == 0) *flagCnt = 0;
}

// ----------------------------------------------------------- knn filter ----
// r24 = r20 EXACT (HW-validated 151.5-152.2us; session-best total 366.6us).
// Probe series complete (7 levers: waves, tail work, pipelining, branches,
// prefetch depth, occupancy x2 -- all null/negative): this structure's
// ~152us is the floor. Packed (j | apx<<16) u32 slots, one ds_write_b32 per
// slot, bias-fold C-init, branchless predicated tail, zero barriers.
__global__ __launch_bounds__(256, 2) void knn_filter(const u16* __restrict__ Xhi,
                                                     const float* __restrict__ sqn,
                                                     const float* __restrict__ thrA,
                                                     u32* __restrict__ candA,
                                                     int* __restrict__ candCnt) {
    __shared__ u32 listP[256 * CAP + 256];   // packed slots + scrap (33.8 KB)
    __shared__ int cntS[256];

    const int tid = threadIdx.x;
    const int wave = tid >> 6, lane = tid & 63;
    const int quad = lane >> 4, n16 = lane & 15;
    const int itile = blockIdx.x >> 3, chunk = blockIdx.x & 7;
    const int ibase = itile * 256;
    const int wbase = ibase + wave * 64;
    const int jch0 = chunk * JCH;
    const unsigned below = (1u << n16) - 1u;
    const int scrapOff = 256 * CAP + tid;    // per-thread scrap slot

    short8 aF[4][4];
#pragma unroll
    for (int is = 0; is < 4; is++) {
        const u16* arow = Xhi + (size_t)(wbase + is * 16 + n16) * Dd + quad * 8;
#pragma unroll
        for (int ks = 0; ks < 4; ks++) aF[is][ks] = *(const short8*)(arow + ks * 32);
    }
    float nhT[16];                    // -thr/2 per owned row
    int cntReg[16];
#pragma unroll
    for (int is = 0; is < 4; is++)
#pragma unroll
        for (int r = 0; r < 4; r++) {
            nhT[is * 4 + r] = -0.5f * thrA[wbase + is * 16 + quad * 4 + r];
            cntReg[is * 4 + r] = 0;
        }

    const u16* bbase = Xhi + (size_t)(jch0 + n16) * Dd + quad * 8;
    short8 bb[2][4];
    float sj[2];
#pragma unroll
    for (int ks = 0; ks < 4; ks++) bb[0][ks] = *(const short8*)(bbase + ks * 32);
    sj[0] = sqn[jch0 + n16];
#pragma unroll
    for (int ks = 0; ks < 4; ks++) bb[1][ks] = *(const short8*)(bbase + 16 * Dd + ks * 32);
    sj[1] = sqn[jch0 + 16 + n16];

    // acc = dot(i,j) - 0.5*sj  (bias in C-init); rv = -2*acc
    // hit: rv < thr  <=>  acc > -thr/2 = nhT
#define MSTEP(p, gg)                                                           \
    {                                                                          \
        const float bias = -0.5f * sj[p];                                      \
        acc##p[0] = (f32x4){bias, bias, bias, bias};                           \
        acc##p[1] = acc##p[0]; acc##p[2] = acc##p[0]; acc##p[3] = acc##p[0];   \
        _Pragma("unroll")                                                      \
        for (int ks = 0; ks < 4; ks++) {                                       \
            acc##p[0] = __builtin_amdgcn_mfma_f32_16x16x32_bf16(aF[0][ks], bb[p][ks], acc##p[0], 0, 0, 0); \
            acc##p[1] = __builtin_amdgcn_mfma_f32_16x16x32_bf16(aF[1][ks], bb[p][ks], acc##p[1], 0, 0, 0); \
            acc##p[2] = __builtin_amdgcn_mfma_f32_16x16x32_bf16(aF[2][ks], bb[p][ks], acc##p[2], 0, 0, 0); \
            acc##p[3] = __builtin_amdgcn_mfma_f32_16x16x32_bf16(aF[3][ks], bb[p][ks], acc##p[3], 0, 0, 0); \
        }                                                                      \
        {   /* unconditional distance-2 prefetch: Xhi/sqn padded past end */   \
            const u16* nb = bbase + (size_t)((gg) + 2) * 16 * Dd;              \
            bb[p][0] = *(const short8*)(nb);                                   \
            bb[p][1] = *(const short8*)(nb + 32);                              \
            bb[p][2] = *(const short8*)(nb + 64);                              \
            bb[p][3] = *(const short8*)(nb + 96);                              \
            sj[p] = sqn[jch0 + ((gg) + 2) * 16 + n16];                         \
        }                                                                      \
    }

#define TSTEP(p, gg)                                                           \
    {                                                                          \
        const int jj = jch0 + (gg) * 16 + n16;                                 \
        _Pragma("unroll")                                                      \
        for (int is = 0; is < 4; is++) {                                       \
            _Pragma("unroll")                                                  \
            for (int r = 0; r < 4; r++) {                                      \
                const int ir = is * 4 + r;                                     \
                const float av = acc##p[is][r];                                \
                const bool h = av > nhT[ir];                                   \
                const unsigned long long mr = __ballot(h);                     \
                const unsigned qm = (unsigned)(mr >> (quad * 16)) & 0xFFFFu;   \
                const int pos = cntReg[ir] + __popc(qm & below);               \
                const bool wr = h && (pos < CAP);                              \
                const int rowbase = (wave * 64 + is * 16 + quad * 4 + r) * CAP; \
                const int off = wr ? rowbase + pos : scrapOff;                 \
                const u32 pk = (u32)(u16)jj |                                  \
                    ((u32)__builtin_bit_cast(unsigned short, (_Float16)av) << 16); \
                listP[off] = pk;            /* unconditional, predicated addr */ \
                cntReg[ir] += __popc(qm);                                      \
            }                                                                  \
        }                                                                      \
    }

    f32x4 acc0[4], acc1[4];
    MSTEP(0, 0)
    for (int g = 0; g < NG - 2; g += 2) {
        MSTEP(1, g + 1)
        TSTEP(0, g)
        MSTEP(0, g + 2)
        TSTEP(1, g + 1)
    }
    MSTEP(1, NG - 1)
    TSTEP(0, NG - 2)
    TSTEP(1, NG - 1)
#undef MSTEP
#undef TSTEP

    if (n16 == 0) {
#pragma unroll
        for (int is = 0; is < 4; is++)
#pragma unroll
            for (int r = 0; r < 4; r++)
                cntS[wave * 64 + is * 16 + quad * 4 + r] = cntReg[is * 4 + r];
    }
    for (int rl = 0; rl < 64; rl++) {
        const int row = wave * 64 + rl;
        const int n = cntS[row];            // same-wave LDS: no barrier needed
        const int gi = ibase + row;
        if (lane == 0) candCnt[(size_t)gi * JSPLIT + chunk] = n;  // raw (overflow signal)
        if (lane < min(n, CAP))
            candA[((size_t)gi * JSPLIT + chunk) * CAP + lane] = listP[row * CAP + lane];
    }
}

// ----------------------------------------------------------- knn exact -----
// r20 (kept): approx-preselect with packed-u32 gather (j = lo16, apx f16 =
// hi16). S = {apx_rv <= t32 + PMARG} provably contains every true top-32
// member; Phase B exact path identical to r18 -> idx bit-identical.
__global__ __launch_bounds__(256) void knn_exact(const float* __restrict__ X,
                                                 const float* __restrict__ sqn,
                                                 const float* __restrict__ thrA,
                                                 const u32* __restrict__ candA,
                                                 const int* __restrict__ candCnt,
                                                 int* __restrict__ idx_out,
                                                 int* __restrict__ flagCnt,
                                                 int* __restrict__ flagRows) {
    __shared__ u16 sjd[4][128];              // compacted S j-lists, per wave
    const int wave = threadIdx.x >> 6, lane = threadIdx.x & 63;
    const int quad = lane >> 4, n16 = lane & 15;
    const int i = blockIdx.x * 4 + wave;

    // xi quarter (32 floats) in registers; broadcast within quad
    float4 xi[8];
    {
        const float4* xb = (const float4*)(X + (size_t)i * Dd + quad * 32);
#pragma unroll
        for (int u = 0; u < 8; u++) xi[u] = xb[u];
    }
    int pre[JSPLIT];
    bool over = false;
    int M = 0;
#pragma unroll
    for (int k = 0; k < JSPLIT; k++) {
        int c = candCnt[(size_t)i * JSPLIT + k];
        over = over || (c > CAP);
        pre[k] = M;
        M += min(c, CAP);
    }
    over = over || (M > 64 * MAXSLOT);
    if (over) {
        if (lane == 0) { const int f = atomicAdd(flagCnt, 1); flagRows[f] = i; }
        return;
    }
    const float rvT = thrA[i];

    // ---- Phase A: one packed gather; rank approx rv in-register
    float ra[MAXSLOT];
    int jdA[MAXSLOT];
#pragma unroll
    for (int s = 0; s < MAXSLOT; s++) {
        const int c = s * 64 + lane;
        if (c < M) {
            int k = 0;
#pragma unroll
            for (int q = 1; q < JSPLIT; q++) if (c >= pre[q]) k = q;
            const u32 v = candA[((size_t)i * JSPLIT + k) * CAP + (c - pre[k])];
            jdA[s] = (int)(v & 0xFFFFu);
            const _Float16 hf = __builtin_bit_cast(_Float16, (unsigned short)(v >> 16));
            ra[s] = -2.0f * (float)hf;       // approx rv
        } else { ra[s] = INFINITY; jdA[s] = -1; }
    }
    int rkA[MAXSLOT] = {};
    for (int s2 = 0; s2 < 64; s2++) {
        const float o0 = __shfl(ra[0], s2), o1 = __shfl(ra[1], s2);
#pragma unroll
        for (int s = 0; s < MAXSLOT; s++) {
            const int myid = lane + 64 * s;
            rkA[s] += (o0 < ra[s] || (o0 == ra[s] && s2 < myid)) ? 1 : 0;
            rkA[s] += (o1 < ra[s] || (o1 == ra[s] && s2 + 64 < myid)) ? 1 : 0;
        }
    }
    float t32 = INFINITY;
    if (M >= Kk) {
        const unsigned long long m0 = __ballot(rkA[0] == Kk - 1);
        if (m0) t32 = __shfl(ra[0], __ffsll(m0) - 1);
        else {
            const unsigned long long m1 = __ballot(rkA[1] == Kk - 1);
            t32 = __shfl(ra[1], __ffsll(m1) - 1);
        }
    }
    const float wEnd = t32 + PMARG;

    // ---- compact S into LDS (slot order preserved -> tiebreak order kept)
    int ns;
    {
        const bool sel0 = ra[0] <= wEnd;
        const unsigned long long b0 = __ballot(sel0);
        const int c0 = __popcll(b0);
        const int p0 = __popcll(b0 & ((1ull << lane) - 1ull));
        const bool sel1 = ra[1] <= wEnd;
        const unsigned long long b1 = __ballot(sel1);
        const int p1 = c0 + __popcll(b1 & ((1ull << lane) - 1ull));
        ns = c0 + __popcll(b1);
        if (sel0) sjd[wave][p0] = (u16)jdA[0];
        if (sel1) sjd[wave][p1] = (u16)jdA[1];
    }

    // ---- Phase B: exact gather over S only (same numerics as r18)
    float rv[MAXSLOT];
    int jd[MAXSLOT];
#pragma unroll
    for (int s = 0; s < MAXSLOT; s++) { rv[s] = INFINITY; jd[s] = -1; }

#pragma unroll
    for (int s = 0; s < MAXSLOT; s++) {
#pragma unroll
        for (int t = 0; t < 4; t++) {
            const int c = s * 64 + t * 16 + n16;
            if (c < ns) {
                const int jj = sjd[wave][c];
                const float4* xb = (const float4*)(X + (size_t)jj * Dd + quad * 32);
                float s0 = 0.f, s1 = 0.f, s2 = 0.f, s3 = 0.f;
#pragma unroll
                for (int u = 0; u < 8; u++) {
                    const float4 b = xb[u];
                    s0 = fmaf(xi[u].x, b.x, s0); s1 = fmaf(xi[u].y, b.y, s1);
                    s2 = fmaf(xi[u].z, b.z, s2); s3 = fmaf(xi[u].w, b.w, s3);
                }
                float p = (s0 + s1) + (s2 + s3);
                p += __shfl_xor(p, 16);
                p += __shfl_xor(p, 32);
                if (quad == t) { rv[s] = fmaf(-2.f, p, sqn[jj]); jd[s] = jj; }
            }
        }
    }

    int good = 0;
#pragma unroll
    for (int s = 0; s < MAXSLOT; s++) good += __popcll(__ballot(rv[s] < rvT - BAND));
    if (good < Kk) {   // insufficient evidence -> exact cleanup path
        if (lane == 0) { const int f = atomicAdd(flagCnt, 1); flagRows[f] = i; }
        return;
    }
    int rk[MAXSLOT] = {};
    for (int s2 = 0; s2 < 64; s2++) {
        float ov[MAXSLOT];
#pragma unroll
        for (int s = 0; s < MAXSLOT; s++) ov[s] = __shfl(rv[s], s2);
#pragma unroll
        for (int s = 0; s < MAXSLOT; s++) {
            const int myid = lane + 64 * s;
#pragma unroll
            for (int t = 0; t < MAXSLOT; t++)
                rk[s] += (ov[t] < rv[s] || (ov[t] == rv[s] && s2 + 64 * t < myid)) ? 1 : 0;
        }
    }
#pragma unroll
    for (int s = 0; s < MAXSLOT; s++)
        if (jd[s] >= 0 && rk[s] < Kk) idx_out[(size_t)i * Kk + rk[s]] = jd[s];
}

// ----------------------------------------------------------- knn cleanup ---
// Exact fp32 full-scan top-32 for flagged rows (expected: none).
__global__ __launch_bounds__(256) void knn_cleanup(const float* __restrict__ X,
                                                   const float* __restrict__ sqn,
                                                   const int* __restrict__ flagCnt,
                                                   const int* __restrict__ flagRows,
                                                   float* __restrict__ scratch,
                                                   int* __restrict__ idx_out) {
    __shared__ float xi[Dd];
    __shared__ int cntS;
    __shared__ float lv[256];
    __shared__ int lj[256];
    const int tid = threadIdx.x;
    const int lane = tid & 63;
    const int F = *flagCnt;
    float* rvS = scratch + (size_t)blockIdx.x * Nn;
    for (int f = blockIdx.x; f < F; f += gridDim.x) {
        const int i = flagRows[f];
        __syncthreads();
        if (tid < Dd) xi[tid] = X[(size_t)i * Dd + tid];
        __syncthreads();
        for (int j = tid; j < Nn; j += 256) {
            const float* xj = X + (size_t)j * Dd;
            float s0 = 0.f, s1 = 0.f, s2 = 0.f, s3 = 0.f;
#pragma unroll
            for (int d = 0; d < Dd; d += 4) {
                const float4 a = *(const float4*)&xi[d];
                const float4 b = *(const float4*)(xj + d);
                s0 = fmaf(a.x, b.x, s0); s1 = fmaf(a.y, b.y, s1);
                s2 = fmaf(a.z, b.z, s2); s3 = fmaf(a.w, b.w, s3);
            }
            rvS[j] = fmaf(-2.f, (s0 + s1) + (s2 + s3), sqn[j]);
        }
        __syncthreads();
        float lo = -1.0e9f, hi = 1.0e9f, T = 1.0e9f;
        for (int it = 0; it < 48; it++) {
            const float mid = 0.5f * (lo + hi);
            int local = 0;
            for (int j = tid; j < Nn; j += 256) local += (rvS[j] < mid) ? 1 : 0;
#pragma unroll
            for (int o = 32; o > 0; o >>= 1) local += __shfl_down(local, o);
            __syncthreads();
            if (tid == 0) cntS = 0;
            __syncthreads();
            if (lane == 0) atomicAdd(&cntS, local);
            __syncthreads();
            const int c = cntS;
            if (c < Kk) lo = mid;
            else if (c > 200) hi = mid;
            else { T = mid; break; }
        }
        if (T == 1.0e9f) T = hi;
        __syncthreads();
        if (tid == 0) cntS = 0;
        __syncthreads();
        for (int j = tid; j < Nn; j += 256) {
            if (rvS[j] < T) {
                const int p = atomicAdd(&cntS, 1);
                if (p < 256) { lv[p] = rvS[j]; lj[p] = j; }
            }
        }
        __syncthreads();
        const int n = min(cntS, 256);
        if (tid < 64) {
            float v[4]; int jjj[4]; int rk2[4] = {0, 0, 0, 0};
#pragma unroll
            for (int s = 0; s < 4; s++) {
                const int sl = lane + 64 * s;
                v[s] = (sl < n) ? lv[sl] : INFINITY;
                jjj[s] = (sl < n) ? lj[sl] : -1;
            }
            for (int s2 = 0; s2 < 64; s2++) {
                const float o0 = __shfl(v[0], s2), o1 = __shfl(v[1], s2);
                const float o2 = __shfl(v[2], s2), o3 = __shfl(v[3], s2);
#pragma unroll
                for (int s = 0; s < 4; s++) {
                    const int myid = lane + 64 * s;
                    rk2[s] += (o0 < v[s] || (o0 == v[s] && s2 < myid));
                    rk2[s] += (o1 < v[s] || (o1 == v[s] && s2 + 64 < myid));
                    rk2[s] += (o2 < v[s] || (o2 == v[s] && s2 + 128 < myid));
                    rk2[s] += (o3 < v[s] || (o3 == v[s] && s2 + 192 < myid));
                }
            }
#pragma unroll
            for (int s = 0; s < 4; s++)
                if (jjj[s] >= 0 && rk2[s] < Kk) idx_out[(size_t)i * Kk + rk2[s]] = jjj[s];
        }
        __syncthreads();
    }
}

// ------------------------------------------------- P = X@(W1a-W1b)+b1, Q = X@W1b
// r19/r20 (validated): 32 rows/block, grid 512 = 2 blocks/CU. r23's 64-row
// variant (grid 256 = 1 block/CU) regressed +48us -- occupancy beats traffic
// amortization for this short streaming kernel.
__global__ __launch_bounds__(256) void pq_kernel(const float* __restrict__ X,
                                                 const float* __restrict__ W1,
                                                 const float* __restrict__ b1,
                                                 float* __restrict__ P,
                                                 float* __restrict__ Q) {
    __shared__ float xrow[32][Dd];   // 16 KB
    const int i0 = blockIdx.x * 32;
    for (int t = threadIdx.x; t < 32 * Dd / 4; t += 256)
        ((float4*)&xrow[0][0])[t] = ((const float4*)(X + (size_t)i0 * Dd))[t];
    __syncthreads();
    const int cc = threadIdx.x & 127;
    const int mat = threadIdx.x >> 7;
    float acc[32];
#pragma unroll
    for (int r = 0; r < 32; r++) acc[r] = 0.f;
    for (int d = 0; d < Dd; d++) {
        float w;
        if (mat == 0) w = W1[d * 128 + cc] - W1[(128 + d) * 128 + cc];
        else          w = W1[(128 + d) * 128 + cc];
#pragma unroll
        for (int r = 0; r < 32; r++) acc[r] = fmaf(xrow[r][d], w, acc[r]);
    }
    if (mat == 0) {
        const float b = b1[cc];
#pragma unroll
        for (int r = 0; r < 32; r++) P[(size_t)(i0 + r) * 128 + cc] = acc[r] + b;
    } else {
#pragma unroll
        for (int r = 0; r < 32; r++) Q[(size_t)(i0 + r) * 128 + cc] = acc[r];
    }
}

// ------- r19 FUSED (kept): h1 in-LDS, then P2/Q2. Deletes h1 kernel + 16 MB.
__global__ __launch_bounds__(256) void pq2_kernel(const float* __restrict__ P,
                                                  const float* __restrict__ Q,
                                                  const int* __restrict__ idx,
                                                  const float* __restrict__ W2,
                                                  const float* __restrict__ b2,
                                                  float* __restrict__ P2,
                                                  float* __restrict__ Q2) {
    __shared__ float w2s[2560];        // 256 x 10, linear
    __shared__ float h1s[16][132];
    __shared__ int jbS[16][Kk];        // 2 KB
    const int i0 = blockIdx.x * 16;
    const int tid = threadIdx.x;
    for (int t = tid; t < 640; t += 256)
        ((float4*)w2s)[t] = ((const float4*)W2)[t];
    ((int2*)&jbS[0][0])[tid] = ((const int2*)(idx + (size_t)i0 * Kk))[tid];  // 512 ints
    __syncthreads();
    {   // h1 rows in LDS: thread -> (row r, 8 cols at c0)
        const int r = tid >> 4, c0 = (tid & 15) * 8;
        float4 m0 = {-INFINITY, -INFINITY, -INFINITY, -INFINITY}, m1 = m0;
        for (int k = 0; k < Kk; k++) {
            const int jb = jbS[r][k];
            const float4* qb = (const float4*)(Q + (size_t)jb * 128 + c0);
            const float4 a = qb[0], b = qb[1];
            m0.x = fmaxf(m0.x, a.x); m0.y = fmaxf(m0.y, a.y);
            m0.z = fmaxf(m0.z, a.z); m0.w = fmaxf(m0.w, a.w);
            m1.x = fmaxf(m1.x, b.x); m1.y = fmaxf(m1.y, b.y);
            m1.z = fmaxf(m1.z, b.z); m1.w = fmaxf(m1.w, b.w);
        }
        const float4* pb = (const float4*)(P + (size_t)(i0 + r) * 128 + c0);
        const float4 pa = pb[0], pc = pb[1];
        h1s[r][c0 + 0] = fmaxf(pa.x + m0.x, 0.f);
        h1s[r][c0 + 1] = fmaxf(pa.y + m0.y, 0.f);
        h1s[r][c0 + 2] = fmaxf(pa.z + m0.z, 0.f);
        h1s[r][c0 + 3] = fmaxf(pa.w + m0.w, 0.f);
        h1s[r][c0 + 4] = fmaxf(pc.x + m1.x, 0.f);
        h1s[r][c0 + 5] = fmaxf(pc.y + m1.y, 0.f);
        h1s[r][c0 + 6] = fmaxf(pc.z + m1.z, 0.f);
        h1s[r][c0 + 7] = fmaxf(pc.w + m1.w, 0.f);
    }
    __syncthreads();
    const int il = tid >> 4, c = tid & 15;
    if (c >= 10) return;
    float pa = 0.f, pb = 0.f;
#pragma unroll 4
    for (int d = 0; d < Dd; d++) {
        const float h = h1s[il][d];
        const float wa = w2s[d * 10 + c];
        const float wb = w2s[(128 + d) * 10 + c];
        pa = fmaf(h, wa - wb, pa);
        pb = fmaf(h, wb, pb);
    }
    P2[(size_t)(i0 + il) * 10 + c] = pa + b2[c];
    Q2[(size_t)(i0 + il) * 10 + c] = pb;
}

// ---------------------------------- out = P2 + max_k Q2[idx] (no relu) ------
__global__ __launch_bounds__(256) void out_kernel(const float* __restrict__ P2,
                                                  const float* __restrict__ Q2,
                                                  const int* __restrict__ idx,
                                                  float* __restrict__ out) {
    const int g = blockIdx.x * 256 + threadIdx.x;
    const int i = g >> 4;
    const int c = g & 15;
    if (c >= 10) return;
    const int* jr = idx + (size_t)i * Kk;
    float m = -INFINITY;
#pragma unroll
    for (int k = 0; k < Kk; k++) m = fmaxf(m, Q2[(size_t)jr[k] * 10 + c]);
    out[(size_t)i * 10 + c] = P2[(size_t)i * 10 + c] + m;
}

extern "C" void kernel_launch(void* const* d_in, const int* in_sizes, int n_in,
                              void* d_out, int out_size, void* d_ws, size_t ws_size,
                              hipStream_t stream) {
    const float* X  = (const float*)d_in[0];
    const float* W1 = (const float*)d_in[1];
    const float* b1 = (const float*)d_in[2];
    const float* W2 = (const float*)d_in[3];
    const float* b2 = (const float*)d_in[4];
    float* out = (float*)d_out;

    char* ws = (char*)d_ws;
    float* sqn     = (float*)(ws + 0);            // 64 KB + pad (prefetch overrun)
    float* thrA    = (float*)(ws + 73728);        // 64 KB
    int*   flagCnt = (int*)(ws + 139264);         // 128 B
    int*   flagRows= (int*)(ws + 139392);         // 64 KB
    int*   idx     = (int*)(ws + 262144);         // 2 MB
    u16*   Xhi     = (u16*)(ws + 2359296);        // (16384+32)*256 B (padded)
    float* P       = (float*)(ws + 6561792);      // 8 MB
    float* Q       = P + (size_t)Nn * 128;        // 8 MB
    // h1 array DELETED (fused into pq2); its 8 MB hole holds candCnt.
    float* P2      = P + (size_t)3 * Nn * 128;    // 640 KB (old offset kept)
    float* Q2      = P2 + (size_t)Nn * 10;        // 640 KB
    // candA packed u32 (16.78 MB) aliases the P+Q span EXACTLY
    // (Nn*8*32*4 B == 2*Nn*128*4 B); dead before pq writes P/Q. candCnt
    // (512 KB) in the h1 hole. cleanup scratch aliases P+Q (candA dead then).
    u32* candA   = (u32*)P;
    int* candCnt = (int*)((char*)P + (size_t)2 * Nn * 128 * 4);  // h1 hole
    float* cleanupScratch = P;                    // 256 blocks x 64 KB = 16 MB

    prep_kernel<<<Nn / 4, 256, 0, stream>>>(X, Xhi, sqn, thrA, flagCnt);
    knn_filter<<<64 * JSPLIT, 256, 0, stream>>>(Xhi, sqn, thrA, candA, candCnt);
    knn_exact<<<Nn / 4, 256, 0, stream>>>(X, sqn, thrA, candA, candCnt, idx, flagCnt, flagRows);
    knn_cleanup<<<256, 256, 0, stream>>>(X, sqn, flagCnt, flagRows, cleanupScratch, idx);
    pq_kernel<<<Nn / 32, 256, 0, stream>>>(X, W1, b1, P, Q);
    pq2_kernel<<<Nn / 16, 256, 0, stream>>>(P, Q, idx, W2, b2, P2, Q2);
    out_kernel<<<Nn * 16 / 256, 256, 0, stream>>>(P2, Q2, idx, out);
}

// Round 17
// 362.189 us; speedup vs baseline: 1.1446x; 1.0160x over previous
//
#include <hip/hip_runtime.h>
#include <math.h>

#define Nn 16384
#define Dd 128
#define Kk 32
#define JSPLIT 8
#define JCH (Nn / JSPLIT)     // 2048 j per chunk
#define NG (JCH / 16)         // 128 groups of 16 j per chunk
#define CAP 32                // cand slots per (row, chunk); true mean ~10.3 (6.8 sigma)
#define MAXSLOT 2             // exact-pass capacity 128 (true mean M~82, 5.1 sigma)
#define BAND 0.4f             // 2x bound on hi-bf16 approx rv error (validated r4-r11)
#define PMARG 1.0f            // preselect window: 2x (BAND + f16-storage err 0.04) rounded up
#define ZQ 2.4176f            // validated: true E[count]~82 (chi-square left tail);
                              // r16's 2.60 gave E~44 -> cleanup blowup. Do not raise.

typedef unsigned short u16;
typedef unsigned u32;
typedef short short8 __attribute__((ext_vector_type(8)));
typedef float f32x4 __attribute__((ext_vector_type(4)));

__device__ __forceinline__ u16 f2bf(float x) {
    unsigned u = __float_as_uint(x);
    unsigned r = u + 0x7FFFu + ((u >> 16) & 1u);   // RN-even
    return (u16)(r >> 16);
}

// --------------- prep: bf16 convert + sqn + analytic threshold + flag=0 ----
__global__ __launch_bounds__(256) void prep_kernel(const float* __restrict__ X,
                                                   u16* __restrict__ Xhi,
                                                   float* __restrict__ sqn,
                                                   float* __restrict__ thrA,
                                                   int* __restrict__ flagCnt) {
    const int i = blockIdx.x * 4 + (threadIdx.x >> 6);
    const int lane = threadIdx.x & 63;
    const float2 v = *(const float2*)(X + (size_t)i * Dd + lane * 2);
    const unsigned pack = ((unsigned)f2bf(v.y) << 16) | (unsigned)f2bf(v.x);
    *(unsigned*)(Xhi + (size_t)i * Dd + lane * 2) = pack;
    float s = fmaf(v.x, v.x, v.y * v.y);
#pragma unroll
    for (int o = 32; o > 0; o >>= 1) s += __shfl_down(s, o);
    if (lane == 0) {
        sqn[i] = s;
        // rv = sqn_j - 2 xi.xj ~ N(128, 256 + 4*sqn_i); keep rv < thr
        thrA[i] = 128.0f - ZQ * sqrtf(256.0f + 4.0f * s);
    }
    if (blockIdx.x == 0 && threadIdx.x == 0) *flagCnt = 0;
}

// ----------------------------------------------------------- knn filter ----
// r25: r20 core + r13's SCALAR-GATED tail (the two fastest validated tail
// variants recombined). r13's gated tail measured 142.2us (fastest filter of
// the session); the branchless form that replaced it measured 145.5-146.2
// and, with the apx pack added (r20), 152.4 -- the unconditional scrap
// writes + pack on every non-hit lane cost ~7us. Gate restored: ~88% of
// row-ballots are all-zero -> one uniform s_cbranch skips qm-extract, pack,
// and the LDS write entirely. Semantics identical (cntReg unchanged when
// qm==0; stores only for hits; slot order preserved).
__global__ __launch_bounds__(256, 2) void knn_filter(const u16* __restrict__ Xhi,
                                                     const float* __restrict__ sqn,
                                                     const float* __restrict__ thrA,
                                                     u32* __restrict__ candA,
                                                     int* __restrict__ candCnt) {
    __shared__ u32 listP[256 * CAP];         // packed slots (32.8 KB; no scrap needed)
    __shared__ int cntS[256];

    const int tid = threadIdx.x;
    const int wave = tid >> 6, lane = tid & 63;
    const int quad = lane >> 4, n16 = lane & 15;
    const int itile = blockIdx.x >> 3, chunk = blockIdx.x & 7;
    const int ibase = itile * 256;
    const int wbase = ibase + wave * 64;
    const int jch0 = chunk * JCH;
    const unsigned below = (1u << n16) - 1u;

    short8 aF[4][4];
#pragma unroll
    for (int is = 0; is < 4; is++) {
        const u16* arow = Xhi + (size_t)(wbase + is * 16 + n16) * Dd + quad * 8;
#pragma unroll
        for (int ks = 0; ks < 4; ks++) aF[is][ks] = *(const short8*)(arow + ks * 32);
    }
    float nhT[16];                    // -thr/2 per owned row
    int cntReg[16];
#pragma unroll
    for (int is = 0; is < 4; is++)
#pragma unroll
        for (int r = 0; r < 4; r++) {
            nhT[is * 4 + r] = -0.5f * thrA[wbase + is * 16 + quad * 4 + r];
            cntReg[is * 4 + r] = 0;
        }

    const u16* bbase = Xhi + (size_t)(jch0 + n16) * Dd + quad * 8;
    short8 bb[2][4];
    float sj[2];
#pragma unroll
    for (int ks = 0; ks < 4; ks++) bb[0][ks] = *(const short8*)(bbase + ks * 32);
    sj[0] = sqn[jch0 + n16];
#pragma unroll
    for (int ks = 0; ks < 4; ks++) bb[1][ks] = *(const short8*)(bbase + 16 * Dd + ks * 32);
    sj[1] = sqn[jch0 + 16 + n16];

    // acc = dot(i,j) - 0.5*sj  (bias in C-init); rv = -2*acc
    // hit: rv < thr  <=>  acc > -thr/2 = nhT
#define MSTEP(p, gg)                                                           \
    {                                                                          \
        const float bias = -0.5f * sj[p];                                      \
        acc##p[0] = (f32x4){bias, bias, bias, bias};                           \
        acc##p[1] = acc##p[0]; acc##p[2] = acc##p[0]; acc##p[3] = acc##p[0];   \
        _Pragma("unroll")                                                      \
        for (int ks = 0; ks < 4; ks++) {                                       \
            acc##p[0] = __builtin_amdgcn_mfma_f32_16x16x32_bf16(aF[0][ks], bb[p][ks], acc##p[0], 0, 0, 0); \
            acc##p[1] = __builtin_amdgcn_mfma_f32_16x16x32_bf16(aF[1][ks], bb[p][ks], acc##p[1], 0, 0, 0); \
            acc##p[2] = __builtin_amdgcn_mfma_f32_16x16x32_bf16(aF[2][ks], bb[p][ks], acc##p[2], 0, 0, 0); \
            acc##p[3] = __builtin_amdgcn_mfma_f32_16x16x32_bf16(aF[3][ks], bb[p][ks], acc##p[3], 0, 0, 0); \
        }                                                                      \
        {   /* unconditional distance-2 prefetch: Xhi/sqn padded past end */   \
            const u16* nb = bbase + (size_t)((gg) + 2) * 16 * Dd;              \
            bb[p][0] = *(const short8*)(nb);                                   \
            bb[p][1] = *(const short8*)(nb + 32);                              \
            bb[p][2] = *(const short8*)(nb + 64);                              \
            bb[p][3] = *(const short8*)(nb + 96);                              \
            sj[p] = sqn[jch0 + ((gg) + 2) * 16 + n16];                         \
        }                                                                      \
    }

#define TSTEP(p, gg)                                                           \
    {                                                                          \
        const int jj = jch0 + (gg) * 16 + n16;                                 \
        _Pragma("unroll")                                                      \
        for (int is = 0; is < 4; is++) {                                       \
            _Pragma("unroll")                                                  \
            for (int r = 0; r < 4; r++) {                                      \
                const int ir = is * 4 + r;                                     \
                const float av = acc##p[is][r];                                \
                const bool h = av > nhT[ir];                                   \
                const unsigned long long mr = __ballot(h);                     \
                if (mr) {   /* uniform scalar gate: ~88% of ballots are 0 */   \
                    const unsigned qm = (unsigned)(mr >> (quad * 16)) & 0xFFFFu; \
                    if (h) {                                                   \
                        const int pos = cntReg[ir] + __popc(qm & below);       \
                        if (pos < CAP) {                                       \
                            const u32 pk = (u32)(u16)jj |                      \
                                ((u32)__builtin_bit_cast(unsigned short, (_Float16)av) << 16); \
                            listP[(wave * 64 + is * 16 + quad * 4 + r) * CAP + pos] = pk; \
                        }                                                      \
                    }                                                          \
                    cntReg[ir] += __popc(qm);                                  \
                }                                                              \
            }                                                                  \
        }                                                                      \
    }

    f32x4 acc0[4], acc1[4];
    MSTEP(0, 0)
    for (int g = 0; g < NG - 2; g += 2) {
        MSTEP(1, g + 1)
        TSTEP(0, g)
        MSTEP(0, g + 2)
        TSTEP(1, g + 1)
    }
    MSTEP(1, NG - 1)
    TSTEP(0, NG - 2)
    TSTEP(1, NG - 1)
#undef MSTEP
#undef TSTEP

    if (n16 == 0) {
#pragma unroll
        for (int is = 0; is < 4; is++)
#pragma unroll
            for (int r = 0; r < 4; r++)
                cntS[wave * 64 + is * 16 + quad * 4 + r] = cntReg[is * 4 + r];
    }
    for (int rl = 0; rl < 64; rl++) {
        const int row = wave * 64 + rl;
        const int n = cntS[row];            // same-wave LDS: no barrier needed
        const int gi = ibase + row;
        if (lane == 0) candCnt[(size_t)gi * JSPLIT + chunk] = n;  // raw (overflow signal)
        if (lane < min(n, CAP))
            candA[((size_t)gi * JSPLIT + chunk) * CAP + lane] = listP[row * CAP + lane];
    }
}

// ----------------------------------------------------------- knn exact -----
// r20 (kept): approx-preselect with packed-u32 gather (j = lo16, apx f16 =
// hi16). S = {apx_rv <= t32 + PMARG} provably contains every true top-32
// member; Phase B exact path identical to r18 -> idx bit-identical.
__global__ __launch_bounds__(256) void knn_exact(const float* __restrict__ X,
                                                 const float* __restrict__ sqn,
                                                 const float* __restrict__ thrA,
                                                 const u32* __restrict__ candA,
                                                 const int* __restrict__ candCnt,
                                                 int* __restrict__ idx_out,
                                                 int* __restrict__ flagCnt,
                                                 int* __restrict__ flagRows) {
    __shared__ u16 sjd[4][128];              // compacted S j-lists, per wave
    const int wave = threadIdx.x >> 6, lane = threadIdx.x & 63;
    const int quad = lane >> 4, n16 = lane & 15;
    const int i = blockIdx.x * 4 + wave;

    // xi quarter (32 floats) in registers; broadcast within quad
    float4 xi[8];
    {
        const float4* xb = (const float4*)(X + (size_t)i * Dd + quad * 32);
#pragma unroll
        for (int u = 0; u < 8; u++) xi[u] = xb[u];
    }
    int pre[JSPLIT];
    bool over = false;
    int M = 0;
#pragma unroll
    for (int k = 0; k < JSPLIT; k++) {
        int c = candCnt[(size_t)i * JSPLIT + k];
        over = over || (c > CAP);
        pre[k] = M;
        M += min(c, CAP);
    }
    over = over || (M > 64 * MAXSLOT);
    if (over) {
        if (lane == 0) { const int f = atomicAdd(flagCnt, 1); flagRows[f] = i; }
        return;
    }
    const float rvT = thrA[i];

    // ---- Phase A: one packed gather; rank approx rv in-register
    float ra[MAXSLOT];
    int jdA[MAXSLOT];
#pragma unroll
    for (int s = 0; s < MAXSLOT; s++) {
        const int c = s * 64 + lane;
        if (c < M) {
            int k = 0;
#pragma unroll
            for (int q = 1; q < JSPLIT; q++) if (c >= pre[q]) k = q;
            const u32 v = candA[((size_t)i * JSPLIT + k) * CAP + (c - pre[k])];
            jdA[s] = (int)(v & 0xFFFFu);
            const _Float16 hf = __builtin_bit_cast(_Float16, (unsigned short)(v >> 16));
            ra[s] = -2.0f * (float)hf;       // approx rv
        } else { ra[s] = INFINITY; jdA[s] = -1; }
    }
    int rkA[MAXSLOT] = {};
    for (int s2 = 0; s2 < 64; s2++) {
        const float o0 = __shfl(ra[0], s2), o1 = __shfl(ra[1], s2);
#pragma unroll
        for (int s = 0; s < MAXSLOT; s++) {
            const int myid = lane + 64 * s;
            rkA[s] += (o0 < ra[s] || (o0 == ra[s] && s2 < myid)) ? 1 : 0;
            rkA[s] += (o1 < ra[s] || (o1 == ra[s] && s2 + 64 < myid)) ? 1 : 0;
        }
    }
    float t32 = INFINITY;
    if (M >= Kk) {
        const unsigned long long m0 = __ballot(rkA[0] == Kk - 1);
        if (m0) t32 = __shfl(ra[0], __ffsll(m0) - 1);
        else {
            const unsigned long long m1 = __ballot(rkA[1] == Kk - 1);
            t32 = __shfl(ra[1], __ffsll(m1) - 1);
        }
    }
    const float wEnd = t32 + PMARG;

    // ---- compact S into LDS (slot order preserved -> tiebreak order kept)
    int ns;
    {
        const bool sel0 = ra[0] <= wEnd;
        const unsigned long long b0 = __ballot(sel0);
        const int c0 = __popcll(b0);
        const int p0 = __popcll(b0 & ((1ull << lane) - 1ull));
        const bool sel1 = ra[1] <= wEnd;
        const unsigned long long b1 = __ballot(sel1);
        const int p1 = c0 + __popcll(b1 & ((1ull << lane) - 1ull));
        ns = c0 + __popcll(b1);
        if (sel0) sjd[wave][p0] = (u16)jdA[0];
        if (sel1) sjd[wave][p1] = (u16)jdA[1];
    }

    // ---- Phase B: exact gather over S only (same numerics as r18)
    float rv[MAXSLOT];
    int jd[MAXSLOT];
#pragma unroll
    for (int s = 0; s < MAXSLOT; s++) { rv[s] = INFINITY; jd[s] = -1; }

#pragma unroll
    for (int s = 0; s < MAXSLOT; s++) {
#pragma unroll
        for (int t = 0; t < 4; t++) {
            const int c = s * 64 + t * 16 + n16;
            if (c < ns) {
                const int jj = sjd[wave][c];
                const float4* xb = (const float4*)(X + (size_t)jj * Dd + quad * 32);
                float s0 = 0.f, s1 = 0.f, s2 = 0.f, s3 = 0.f;
#pragma unroll
                for (int u = 0; u < 8; u++) {
                    const float4 b = xb[u];
                    s0 = fmaf(xi[u].x, b.x, s0); s1 = fmaf(xi[u].y, b.y, s1);
                    s2 = fmaf(xi[u].z, b.z, s2); s3 = fmaf(xi[u].w, b.w, s3);
                }
                float p = (s0 + s1) + (s2 + s3);
                p += __shfl_xor(p, 16);
                p += __shfl_xor(p, 32);
                if (quad == t) { rv[s] = fmaf(-2.f, p, sqn[jj]); jd[s] = jj; }
            }
        }
    }

    int good = 0;
#pragma unroll
    for (int s = 0; s < MAXSLOT; s++) good += __popcll(__ballot(rv[s] < rvT - BAND));
    if (good < Kk) {   // insufficient evidence -> exact cleanup path
        if (lane == 0) { const int f = atomicAdd(flagCnt, 1); flagRows[f] = i; }
        return;
    }
    int rk[MAXSLOT] = {};
    for (int s2 = 0; s2 < 64; s2++) {
        float ov[MAXSLOT];
#pragma unroll
        for (int s = 0; s < MAXSLOT; s++) ov[s] = __shfl(rv[s], s2);
#pragma unroll
        for (int s = 0; s < MAXSLOT; s++) {
            const int myid = lane + 64 * s;
#pragma unroll
            for (int t = 0; t < MAXSLOT; t++)
                rk[s] += (ov[t] < rv[s] || (ov[t] == rv[s] && s2 + 64 * t < myid)) ? 1 : 0;
        }
    }
#pragma unroll
    for (int s = 0; s < MAXSLOT; s++)
        if (jd[s] >= 0 && rk[s] < Kk) idx_out[(size_t)i * Kk + rk[s]] = jd[s];
}

// ----------------------------------------------------------- knn cleanup ---
// Exact fp32 full-scan top-32 for flagged rows (expected: none).
__global__ __launch_bounds__(256) void knn_cleanup(const float* __restrict__ X,
                                                   const float* __restrict__ sqn,
                                                   const int* __restrict__ flagCnt,
                                                   const int* __restrict__ flagRows,
                                                   float* __restrict__ scratch,
                                                   int* __restrict__ idx_out) {
    __shared__ float xi[Dd];
    __shared__ int cntS;
    __shared__ float lv[256];
    __shared__ int lj[256];
    const int tid = threadIdx.x;
    const int lane = tid & 63;
    const int F = *flagCnt;
    float* rvS = scratch + (size_t)blockIdx.x * Nn;
    for (int f = blockIdx.x; f < F; f += gridDim.x) {
        const int i = flagRows[f];
        __syncthreads();
        if (tid < Dd) xi[tid] = X[(size_t)i * Dd + tid];
        __syncthreads();
        for (int j = tid; j < Nn; j += 256) {
            const float* xj = X + (size_t)j * Dd;
            float s0 = 0.f, s1 = 0.f, s2 = 0.f, s3 = 0.f;
#pragma unroll
            for (int d = 0; d < Dd; d += 4) {
                const float4 a = *(const float4*)&xi[d];
                const float4 b = *(const float4*)(xj + d);
                s0 = fmaf(a.x, b.x, s0); s1 = fmaf(a.y, b.y, s1);
                s2 = fmaf(a.z, b.z, s2); s3 = fmaf(a.w, b.w, s3);
            }
            rvS[j] = fmaf(-2.f, (s0 + s1) + (s2 + s3), sqn[j]);
        }
        __syncthreads();
        float lo = -1.0e9f, hi = 1.0e9f, T = 1.0e9f;
        for (int it = 0; it < 48; it++) {
            const float mid = 0.5f * (lo + hi);
            int local = 0;
            for (int j = tid; j < Nn; j += 256) local += (rvS[j] < mid) ? 1 : 0;
#pragma unroll
            for (int o = 32; o > 0; o >>= 1) local += __shfl_down(local, o);
            __syncthreads();
            if (tid == 0) cntS = 0;
            __syncthreads();
            if (lane == 0) atomicAdd(&cntS, local);
            __syncthreads();
            const int c = cntS;
            if (c < Kk) lo = mid;
            else if (c > 200) hi = mid;
            else { T = mid; break; }
        }
        if (T == 1.0e9f) T = hi;
        __syncthreads();
        if (tid == 0) cntS = 0;
        __syncthreads();
        for (int j = tid; j < Nn; j += 256) {
            if (rvS[j] < T) {
                const int p = atomicAdd(&cntS, 1);
                if (p < 256) { lv[p] = rvS[j]; lj[p] = j; }
            }
        }
        __syncthreads();
        const int n = min(cntS, 256);
        if (tid < 64) {
            float v[4]; int jjj[4]; int rk2[4] = {0, 0, 0, 0};
#pragma unroll
            for (int s = 0; s < 4; s++) {
                const int sl = lane + 64 * s;
                v[s] = (sl < n) ? lv[sl] : INFINITY;
                jjj[s] = (sl < n) ? lj[sl] : -1;
            }
            for (int s2 = 0; s2 < 64; s2++) {
                const float o0 = __shfl(v[0], s2), o1 = __shfl(v[1], s2);
                const float o2 = __shfl(v[2], s2), o3 = __shfl(v[3], s2);
#pragma unroll
                for (int s = 0; s < 4; s++) {
                    const int myid = lane + 64 * s;
                    rk2[s] += (o0 < v[s] || (o0 == v[s] && s2 < myid));
                    rk2[s] += (o1 < v[s] || (o1 == v[s] && s2 + 64 < myid));
                    rk2[s] += (o2 < v[s] || (o2 == v[s] && s2 + 128 < myid));
                    rk2[s] += (o3 < v[s] || (o3 == v[s] && s2 + 192 < myid));
                }
            }
#pragma unroll
            for (int s = 0; s < 4; s++)
                if (jjj[s] >= 0 && rk2[s] < Kk) idx_out[(size_t)i * Kk + rk2[s]] = jjj[s];
        }
        __syncthreads();
    }
}

// ------------------------------------------------- P = X@(W1a-W1b)+b1, Q = X@W1b
// r19/r20 (validated): 32 rows/block, grid 512 = 2 blocks/CU. r23's 64-row
// variant (grid 256 = 1 block/CU) regressed +48us -- occupancy beats traffic
// amortization for this short streaming kernel.
__global__ __launch_bounds__(256) void pq_kernel(const float* __restrict__ X,
                                                 const float* __restrict__ W1,
                                                 const float* __restrict__ b1,
                                                 float* __restrict__ P,
                                                 float* __restrict__ Q) {
    __shared__ float xrow[32][Dd];   // 16 KB
    const int i0 = blockIdx.x * 32;
    for (int t = threadIdx.x; t < 32 * Dd / 4; t += 256)
        ((float4*)&xrow[0][0])[t] = ((const float4*)(X + (size_t)i0 * Dd))[t];
    __syncthreads();
    const int cc = threadIdx.x & 127;
    const int mat = threadIdx.x >> 7;
    float acc[32];
#pragma unroll
    for (int r = 0; r < 32; r++) acc[r] = 0.f;
    for (int d = 0; d < Dd; d++) {
        float w;
        if (mat == 0) w = W1[d * 128 + cc] - W1[(128 + d) * 128 + cc];
        else          w = W1[(128 + d) * 128 + cc];
#pragma unroll
        for (int r = 0; r < 32; r++) acc[r] = fmaf(xrow[r][d], w, acc[r]);
    }
    if (mat == 0) {
        const float b = b1[cc];
#pragma unroll
        for (int r = 0; r < 32; r++) P[(size_t)(i0 + r) * 128 + cc] = acc[r] + b;
    } else {
#pragma unroll
        for (int r = 0; r < 32; r++) Q[(size_t)(i0 + r) * 128 + cc] = acc[r];
    }
}

// ------- r19 FUSED (kept): h1 in-LDS, then P2/Q2. Deletes h1 kernel + 16 MB.
__global__ __launch_bounds__(256) void pq2_kernel(const float* __restrict__ P,
                                                  const float* __restrict__ Q,
                                                  const int* __restrict__ idx,
                                                  const float* __restrict__ W2,
                                                  const float* __restrict__ b2,
                                                  float* __restrict__ P2,
                                                  float* __restrict__ Q2) {
    __shared__ float w2s[2560];        // 256 x 10, linear
    __shared__ float h1s[16][132];
    __shared__ int jbS[16][Kk];        // 2 KB
    const int i0 = blockIdx.x * 16;
    const int tid = threadIdx.x;
    for (int t = tid; t < 640; t += 256)
        ((float4*)w2s)[t] = ((const float4*)W2)[t];
    ((int2*)&jbS[0][0])[tid] = ((const int2*)(idx + (size_t)i0 * Kk))[tid];  // 512 ints
    __syncthreads();
    {   // h1 rows in LDS: thread -> (row r, 8 cols at c0)
        const int r = tid >> 4, c0 = (tid & 15) * 8;
        float4 m0 = {-INFINITY, -INFINITY, -INFINITY, -INFINITY}, m1 = m0;
        for (int k = 0; k < Kk; k++) {
            const int jb = jbS[r][k];
            const float4* qb = (const float4*)(Q + (size_t)jb * 128 + c0);
            const float4 a = qb[0], b = qb[1];
            m0.x = fmaxf(m0.x, a.x); m0.y = fmaxf(m0.y, a.y);
            m0.z = fmaxf(m0.z, a.z); m0.w = fmaxf(m0.w, a.w);
            m1.x = fmaxf(m1.x, b.x); m1.y = fmaxf(m1.y, b.y);
            m1.z = fmaxf(m1.z, b.z); m1.w = fmaxf(m1.w, b.w);
        }
        const float4* pb = (const float4*)(P + (size_t)(i0 + r) * 128 + c0);
        const float4 pa = pb[0], pc = pb[1];
        h1s[r][c0 + 0] = fmaxf(pa.x + m0.x, 0.f);
        h1s[r][c0 + 1] = fmaxf(pa.y + m0.y, 0.f);
        h1s[r][c0 + 2] = fmaxf(pa.z + m0.z, 0.f);
        h1s[r][c0 + 3] = fmaxf(pa.w + m0.w, 0.f);
        h1s[r][c0 + 4] = fmaxf(pc.x + m1.x, 0.f);
        h1s[r][c0 + 5] = fmaxf(pc.y + m1.y, 0.f);
        h1s[r][c0 + 6] = fmaxf(pc.z + m1.z, 0.f);
        h1s[r][c0 + 7] = fmaxf(pc.w + m1.w, 0.f);
    }
    __syncthreads();
    const int il = tid >> 4, c = tid & 15;
    if (c >= 10) return;
    float pa = 0.f, pb = 0.f;
#pragma unroll 4
    for (int d = 0; d < Dd; d++) {
        const float h = h1s[il][d];
        const float wa = w2s[d * 10 + c];
        const float wb = w2s[(128 + d) * 10 + c];
        pa = fmaf(h, wa - wb, pa);
        pb = fmaf(h, wb, pb);
    }
    P2[(size_t)(i0 + il) * 10 + c] = pa + b2[c];
    Q2[(size_t)(i0 + il) * 10 + c] = pb;
}

// ---------------------------------- out = P2 + max_k Q2[idx] (no relu) ------
__global__ __launch_bounds__(256) void out_kernel(const float* __restrict__ P2,
                                                  const float* __restrict__ Q2,
                                                  const int* __restrict__ idx,
                                                  float* __restrict__ out) {
    const int g = blockIdx.x * 256 + threadIdx.x;
    const int i = g >> 4;
    const int c = g & 15;
    if (c >= 10) return;
    const int* jr = idx + (size_t)i * Kk;
    float m = -INFINITY;
#pragma unroll
    for (int k = 0; k < Kk; k++) m = fmaxf(m, Q2[(size_t)jr[k] * 10 + c]);
    out[(size_t)i * 10 + c] = P2[(size_t)i * 10 + c] + m;
}

extern "C" void kernel_launch(void* const* d_in, const int* in_sizes, int n_in,
                              void* d_out, int out_size, void* d_ws, size_t ws_size,
                              hipStream_t stream) {
    const float* X  = (const float*)d_in[0];
    const float* W1 = (const float*)d_in[1];
    const float* b1 = (const float*)d_in[2];
    const float* W2 = (const float*)d_in[3];
    const float* b2 = (const float*)d_in[4];
    float* out = (float*)d_out;

    char* ws = (char*)d_ws;
    float* sqn     = (float*)(ws + 0);            // 64 KB + pad (prefetch overrun)
    float* thrA    = (float*)(ws + 73728);        // 64 KB
    int*   flagCnt = (int*)(ws + 139264);         // 128 B
    int*   flagRows= (int*)(ws + 139392);         // 64 KB
    int*   idx     = (int*)(ws + 262144);         // 2 MB
    u16*   Xhi     = (u16*)(ws + 2359296);        // (16384+32)*256 B (padded)
    float* P       = (float*)(ws + 6561792);      // 8 MB
    float* Q       = P + (size_t)Nn * 128;        // 8 MB
    // h1 array DELETED (fused into pq2); its 8 MB hole holds candCnt.
    float* P2      = P + (size_t)3 * Nn * 128;    // 640 KB (old offset kept)
    float* Q2      = P2 + (size_t)Nn * 10;        // 640 KB
    // candA packed u32 (16.78 MB) aliases the P+Q span EXACTLY
    // (Nn*8*32*4 B == 2*Nn*128*4 B); dead before pq writes P/Q. candCnt
    // (512 KB) in the h1 hole. cleanup scratch aliases P+Q (candA dead then).
    u32* candA   = (u32*)P;
    int* candCnt = (int*)((char*)P + (size_t)2 * Nn * 128 * 4);  // h1 hole
    float* cleanupScratch = P;                    // 256 blocks x 64 KB = 16 MB

    prep_kernel<<<Nn / 4, 256, 0, stream>>>(X, Xhi, sqn, thrA, flagCnt);
    knn_filter<<<64 * JSPLIT, 256, 0, stream>>>(Xhi, sqn, thrA, candA, candCnt);
    knn_exact<<<Nn / 4, 256, 0, stream>>>(X, sqn, thrA, candA, candCnt, idx, flagCnt, flagRows);
    knn_cleanup<<<256, 256, 0, stream>>>(X, sqn, flagCnt, flagRows, cleanupScratch, idx);
    pq_kernel<<<Nn / 32, 256, 0, stream>>>(X, W1, b1, P, Q);
    pq2_kernel<<<Nn / 16, 256, 0, stream>>>(P, Q, idx, W2, b2, P2, Q2);
    out_kernel<<<Nn * 16 / 256, 256, 0, stream>>>(P2, Q2, idx, out);
}